// Round 4
// baseline (485.779 us; speedup 1.0000x reference)
//
#include <hip/hip_runtime.h>

#define CD   256
#define WD   64
#define NBH  2048
#define GRID 256
#define ITER (NBH / GRID)
#define XST  264   // bf16 row stride for X/T tiles (256+8, keeps rows 16B-aligned)
#define VST  72    // bf16 row stride for Vt (64+8)
#define SST  68    // fp32 row stride for S (64+4)

typedef unsigned short u16;
typedef __attribute__((ext_vector_type(8))) short bfrag_t;  // 8 bf16 = 4 VGPR
typedef __attribute__((ext_vector_type(4))) float f4_t;

#define MFMA(a, b, c) __builtin_amdgcn_mfma_f32_16x16x32_bf16(a, b, c, 0, 0, 0)

__device__ __forceinline__ u16 f2bf(float f) {
    unsigned u = __float_as_uint(f);
    u += 0x7fffu + ((u >> 16) & 1u);          // round-to-nearest-even
    return (u16)(u >> 16);
}
__device__ __forceinline__ float bf2f(u16 h) {
    return __uint_as_float(((unsigned)h) << 16);
}

// ---------------------------------------------------------------------------
// prep_m: Mt[d][c] = sum_f wk[c][f]*wq[d][f], split hi/lo bf16.
// ---------------------------------------------------------------------------
__global__ __launch_bounds__(256) void prep_m(
    const float* __restrict__ wq, const float* __restrict__ wk,
    u16* __restrict__ Mthi, u16* __restrict__ Mtlo)
{
    __shared__ float swq[16 * 257];
    __shared__ float swk[32 * 257];
    const int t = threadIdx.x;
    const int dt = blockIdx.x >> 3;   // 16 d-tiles
    const int ct = blockIdx.x & 7;    // 8 c-tiles (32 c each)
    #pragma unroll
    for (int n = 0; n < 16; ++n) {
        int idx = n * 256 + t;        // 4096
        int d = idx >> 8, f = idx & 255;
        swq[d * 257 + f] = wq[(dt * 16 + d) * CD + f];
    }
    #pragma unroll
    for (int n = 0; n < 32; ++n) {
        int idx = n * 256 + t;        // 8192
        int c = idx >> 8, f = idx & 255;
        swk[c * 257 + f] = wk[(ct * 32 + c) * CD + f];
    }
    __syncthreads();
    const int d = t & 15, c0 = (t >> 4) * 2;
    #pragma unroll
    for (int cc = 0; cc < 2; ++cc) {
        const float* kr = &swk[(c0 + cc) * 257];
        const float* qr = &swq[d * 257];
        float acc = 0.f;
        #pragma unroll 8
        for (int f = 0; f < CD; ++f) acc = fmaf(kr[f], qr[f], acc);
        u16 h = f2bf(acc);
        int off = (dt * 16 + d) * CD + ct * 32 + c0 + cc;
        Mthi[off] = h;
        Mtlo[off] = f2bf(acc - bf2f(h));
    }
}

// prep_v: Wvt[d][c] = bf16(wv[c][d]) via LDS transpose. Grid 16 (4x4 tiles).
__global__ __launch_bounds__(256) void prep_v(
    const float* __restrict__ wv, u16* __restrict__ Wvthi)
{
    __shared__ float tile[64 * 65];
    const int t = threadIdx.x;
    const int bc = blockIdx.x >> 2, bd = blockIdx.x & 3;
    #pragma unroll
    for (int n = 0; n < 16; ++n) {
        int idx = n * 256 + t;
        int c = idx >> 6, d = idx & 63;
        tile[c * 65 + d] = wv[(bc * 64 + c) * CD + bd * 64 + d];
    }
    __syncthreads();
    #pragma unroll
    for (int n = 0; n < 16; ++n) {
        int idx = n * 256 + t;
        int d = idx >> 6, c = idx & 63;
        Wvthi[(bd * 64 + d) * CD + bc * 64 + c] = f2bf(tile[c * 65 + d]);
    }
}

// prep_b: wqbk[c] = sum_f wq[c][f]*bk[f]. Grid 16, coalesced, 16-lane reduce.
__global__ __launch_bounds__(256) void prep_b(
    const float* __restrict__ wq, const float* __restrict__ bk,
    float* __restrict__ wqbk)
{
    __shared__ float sbk[CD];
    const int t = threadIdx.x;
    if (t < CD) sbk[t] = bk[t];
    __syncthreads();
    const int c = blockIdx.x * 16 + (t >> 4), part = t & 15;
    const float* wr = wq + c * CD + part * 16;
    const float* br = sbk + part * 16;
    float a = 0.f;
    #pragma unroll
    for (int j = 0; j < 16; ++j) a = fmaf(wr[j], br[j], a);
    a += __shfl_xor(a, 1);
    a += __shfl_xor(a, 2);
    a += __shfl_xor(a, 4);
    a += __shfl_xor(a, 8);
    if (part == 0) wqbk[c] = a;
}

// ---------------------------------------------------------------------------
// Main: PERSISTENT blocks. Grid 256 (1 block/CU), each block handles 8 bh.
// Per-bh phase structure identical to the best (209 us) kernel, except the
// dedicated stage phase is gone: next-bh x is loaded into registers at the
// top of the PV phase, hidden under PV's MFMA/LDS work and out-writes, and
// written to sXhi/sXlo (dead during PV) before the end-of-iteration barrier.
// sxb is double-buffered (+512 B). Phase S uses 3 independent MFMA chains
// (round-2 lesson: chain ILP matters).
// ---------------------------------------------------------------------------
extern __shared__ char smem_raw[];

__global__ __launch_bounds__(1024, 4) void attn_kernel(
    const float* __restrict__ x,
    const u16* __restrict__ Mthi, const u16* __restrict__ Mtlo,
    const u16* __restrict__ Wvthi, const float* __restrict__ wqbk,
    const float* __restrict__ bv, float* __restrict__ out)
{
    u16* sXhi = (u16*)smem_raw;                 // [64][XST]
    u16* sXlo = sXhi + WD * XST;
    u16* sThi = sXlo + WD * XST;                // [64][XST] token-major T
    u16* sTlo = sThi + WD * XST;
    u16* sVt  = sThi;                           // alias: [256][VST] after S
    float* sS   = (float*)(sTlo + WD * XST);    // [64][SST]
    float* sxb2 = sS + WD * SST;                // [2][64] double-buffered
    float* sbv  = sxb2 + 2 * WD;                // [256]

    const int t = threadIdx.x;
    const int wave = t >> 6, lane = t & 63;
    const int lane15 = lane & 15, quad = lane >> 4;

    if (t < CD) sbv[t] = bv[t];

    // ---- prologue: stage bh0 = blockIdx.x -------------------------------
    {
        const float* __restrict__ xblk = x + (size_t)blockIdx.x * (WD * CD);
        const float4* xv4 = (const float4*)xblk;
        #pragma unroll
        for (int n = 0; n < 4; ++n) {
            int idx = n * 1024 + t;             // 0..4095
            float4 v = xv4[idx];
            int i = idx >> 6;
            int c = (idx & 63) << 2;
            ushort4 h4, l4;
            h4.x = f2bf(v.x); l4.x = f2bf(v.x - bf2f(h4.x));
            h4.y = f2bf(v.y); l4.y = f2bf(v.y - bf2f(h4.y));
            h4.z = f2bf(v.z); l4.z = f2bf(v.z - bf2f(h4.z));
            h4.w = f2bf(v.w); l4.w = f2bf(v.w - bf2f(h4.w));
            *(ushort4*)&sXhi[i * XST + c] = h4;
            *(ushort4*)&sXlo[i * XST + c] = l4;
        }
        const int row = t >> 4, part = t & 15;
        const float* xr = xblk + row * CD + part * 16;
        const float* br = wqbk + part * 16;
        float a = 0.f;
        #pragma unroll
        for (int i = 0; i < 4; ++i) {
            float4 xv = *(const float4*)&xr[i * 4];
            float4 bvv = *(const float4*)&br[i * 4];
            a = fmaf(xv.x, bvv.x, a); a = fmaf(xv.y, bvv.y, a);
            a = fmaf(xv.z, bvv.z, a); a = fmaf(xv.w, bvv.w, a);
        }
        a += __shfl_xor(a, 1);
        a += __shfl_xor(a, 2);
        a += __shfl_xor(a, 4);
        a += __shfl_xor(a, 8);
        if (part == 0) sxb2[row] = a;           // buffer 0
    }
    __syncthreads();

    for (int it = 0; it < ITER; ++it) {
        const int bh = blockIdx.x + (it << 8);
        const float* __restrict__ xblk = x + (size_t)bh * (WD * CD);
        float* __restrict__ oblk = out + (size_t)bh * (WD * CD);
        const float* __restrict__ xnext = x + (size_t)(bh + GRID) * (WD * CD);
        const float* sxb_cur = sxb2 + (it & 1) * WD;
        float* sxb_nxt = sxb2 + ((it + 1) & 1) * WD;

        // ---- Phase T: Tt[d][i] = sum_c Mt[d][c]*X[i][c]  (split, 3 terms)
        // Wave w: d-tile w, all 4 token tiles. 96 MFMAs/wave.
        {
            f4_t acc[4];
            const f4_t z = {0.f, 0.f, 0.f, 0.f};
            #pragma unroll
            for (int a = 0; a < 4; ++a) acc[a] = z;

            const int drow = wave * 16 + lane15;
            #pragma unroll
            for (int kk = 0; kk < 8; ++kk) {
                const int k0 = kk * 32 + quad * 8;
                const int mo = drow * CD + k0;
                bfrag_t Ah = *(const bfrag_t*)(Mthi + mo);
                bfrag_t Al = *(const bfrag_t*)(Mtlo + mo);
                bfrag_t Bh[4], Bl[4];
                #pragma unroll
                for (int nt = 0; nt < 4; ++nt) {
                    const int xo = (nt * 16 + lane15) * XST + k0;
                    Bh[nt] = *(const bfrag_t*)(sXhi + xo);
                    Bl[nt] = *(const bfrag_t*)(sXlo + xo);
                }
                #pragma unroll
                for (int nt = 0; nt < 4; ++nt) {
                    acc[nt] = MFMA(Ah, Bh[nt], acc[nt]);
                    acc[nt] = MFMA(Ah, Bl[nt], acc[nt]);
                    acc[nt] = MFMA(Al, Bh[nt], acc[nt]);
                }
            }
            #pragma unroll
            for (int nt = 0; nt < 4; ++nt) {
                const int i  = nt * 16 + lane15;
                const int d0 = wave * 16 + quad * 4;
                ushort4 h4, l4;
                float f;
                f = acc[nt][0]; h4.x = f2bf(f); l4.x = f2bf(f - bf2f(h4.x));
                f = acc[nt][1]; h4.y = f2bf(f); l4.y = f2bf(f - bf2f(h4.y));
                f = acc[nt][2]; h4.z = f2bf(f); l4.z = f2bf(f - bf2f(h4.z));
                f = acc[nt][3]; h4.w = f2bf(f); l4.w = f2bf(f - bf2f(h4.w));
                *(ushort4*)&sThi[i * XST + d0] = h4;
                *(ushort4*)&sTlo[i * XST + d0] = l4;
            }
        }
        __syncthreads();

        // ---- Phase S: S[w][v] = sum_c T[w][c]*X[v][c] + xb[v] -----------
        // 3 independent accumulator chains (depth 8 instead of 24).
        {
            const f4_t z = {0.f, 0.f, 0.f, 0.f};
            f4_t a0 = z, a1 = z, a2 = z;
            const int m0 = (wave >> 2) * 16;
            const int n0 = (wave & 3) * 16;
            #pragma unroll
            for (int kk = 0; kk < 8; ++kk) {
                const int k0 = kk * 32 + quad * 8;
                const int to = (m0 + lane15) * XST + k0;
                const int xo = (n0 + lane15) * XST + k0;
                bfrag_t Th = *(const bfrag_t*)(sThi + to);
                bfrag_t Tl = *(const bfrag_t*)(sTlo + to);
                bfrag_t Xh = *(const bfrag_t*)(sXhi + xo);
                bfrag_t Xl = *(const bfrag_t*)(sXlo + xo);
                a0 = MFMA(Th, Xh, a0);
                a1 = MFMA(Th, Xl, a1);
                a2 = MFMA(Tl, Xh, a2);
            }
            const int v = n0 + lane15;
            const float xbv = sxb_cur[v];
            #pragma unroll
            for (int r = 0; r < 4; ++r) {
                const int wtok = m0 + quad * 4 + r;
                sS[wtok * SST + v] = a0[r] + a1[r] + a2[r] + xbv;
            }
        }
        __syncthreads();

        // ---- Phase V: Vt[d][j] = sum_c Wvt[d][c]*Xhi[j][c] + bv[d] ------
        // Writes sVt (alias of sThi, safe: S done). 32 MFMAs/wave.
        {
            f4_t acc[4];
            const f4_t z = {0.f, 0.f, 0.f, 0.f};
            #pragma unroll
            for (int a = 0; a < 4; ++a) acc[a] = z;

            const int drow = wave * 16 + lane15;
            #pragma unroll
            for (int kk = 0; kk < 8; ++kk) {
                const int k0 = kk * 32 + quad * 8;
                bfrag_t Af = *(const bfrag_t*)(Wvthi + drow * CD + k0);
                #pragma unroll
                for (int nt = 0; nt < 4; ++nt) {
                    bfrag_t Bf = *(const bfrag_t*)(sXhi + (nt * 16 + lane15) * XST + k0);
                    acc[nt] = MFMA(Af, Bf, acc[nt]);
                }
            }
            #pragma unroll
            for (int nt = 0; nt < 4; ++nt) {
                const int j = nt * 16 + lane15;
                #pragma unroll
                for (int r = 0; r < 4; ++r) {
                    const int d = wave * 16 + quad * 4 + r;
                    sVt[d * VST + j] = f2bf(acc[nt][r] + sbv[d]);
                }
            }
        }
        // ---- softmax over v: 16 lanes per row, 4 elements each ----------
        {
            const int row = t >> 4, part = t & 15;
            float* srow = &sS[row * SST + part * 4];
            float e[4];
            float mx = fmaxf(fmaxf(srow[0], srow[1]), fmaxf(srow[2], srow[3]));
            mx = fmaxf(mx, __shfl_xor(mx, 1));
            mx = fmaxf(mx, __shfl_xor(mx, 2));
            mx = fmaxf(mx, __shfl_xor(mx, 4));
            mx = fmaxf(mx, __shfl_xor(mx, 8));
            float sum = 0.f;
            #pragma unroll
            for (int u = 0; u < 4; ++u) { e[u] = __expf(srow[u] - mx); sum += e[u]; }
            sum += __shfl_xor(sum, 1);
            sum += __shfl_xor(sum, 2);
            sum += __shfl_xor(sum, 4);
            sum += __shfl_xor(sum, 8);
            float inv = 1.0f / sum;
            #pragma unroll
            for (int u = 0; u < 4; ++u) srow[u] = e[u] * inv;
        }
        __syncthreads();

        // ---- Phase PV + pipelined stage of next bh ----------------------
        // PV reads sS/sVt/global-x only; sXhi/sXlo are dead -> overwrite
        // them here with next-bh data, hiding the global latency under PV.
        {
            // (1) issue next-bh x loads early (16 VGPR held through PV)
            float4 xv[4];
            if (it + 1 < ITER) {
                const float4* xnv4 = (const float4*)xnext;
                #pragma unroll
                for (int n = 0; n < 4; ++n) xv[n] = xnv4[n * 1024 + t];
            }

            // (2) PV MFMA: out[w][d] = sum_j P[w][j]*Vt[d][j]
            f4_t acc[4];
            const f4_t z = {0.f, 0.f, 0.f, 0.f};
            #pragma unroll
            for (int a = 0; a < 4; ++a) acc[a] = z;

            const int m0 = (wave & 3) * 16;
            const int nbase = (wave >> 2) * 64;
            #pragma unroll
            for (int kk = 0; kk < 2; ++kk) {
                const int k0 = kk * 32 + quad * 8;
                const float* p = &sS[(m0 + lane15) * SST + k0];
                f4_t p0 = *(const f4_t*)p;
                f4_t p1 = *(const f4_t*)(p + 4);
                bfrag_t Af;
                Af[0] = (short)f2bf(p0[0]); Af[1] = (short)f2bf(p0[1]);
                Af[2] = (short)f2bf(p0[2]); Af[3] = (short)f2bf(p0[3]);
                Af[4] = (short)f2bf(p1[0]); Af[5] = (short)f2bf(p1[1]);
                Af[6] = (short)f2bf(p1[2]); Af[7] = (short)f2bf(p1[3]);
                #pragma unroll
                for (int nt = 0; nt < 4; ++nt) {
                    bfrag_t Bf = *(const bfrag_t*)(sVt + (nbase + nt * 16 + lane15) * VST + k0);
                    acc[nt] = MFMA(Af, Bf, acc[nt]);
                }
            }

            // (3) stage writes for next bh + xb(next)
            if (it + 1 < ITER) {
                #pragma unroll
                for (int n = 0; n < 4; ++n) {
                    int idx = n * 1024 + t;
                    int i = idx >> 6;
                    int c = (idx & 63) << 2;
                    float4 v = xv[n];
                    ushort4 h4, l4;
                    h4.x = f2bf(v.x); l4.x = f2bf(v.x - bf2f(h4.x));
                    h4.y = f2bf(v.y); l4.y = f2bf(v.y - bf2f(h4.y));
                    h4.z = f2bf(v.z); l4.z = f2bf(v.z - bf2f(h4.z));
                    h4.w = f2bf(v.w); l4.w = f2bf(v.w - bf2f(h4.w));
                    *(ushort4*)&sXhi[i * XST + c] = h4;
                    *(ushort4*)&sXlo[i * XST + c] = l4;
                }
                const int row = t >> 4, part = t & 15;
                const float* xr = xnext + row * CD + part * 16;
                const float* br = wqbk + part * 16;
                float a = 0.f;
                #pragma unroll
                for (int i = 0; i < 4; ++i) {
                    float4 xq = *(const float4*)&xr[i * 4];
                    float4 bq = *(const float4*)&br[i * 4];
                    a = fmaf(xq.x, bq.x, a); a = fmaf(xq.y, bq.y, a);
                    a = fmaf(xq.z, bq.z, a); a = fmaf(xq.w, bq.w, a);
                }
                a += __shfl_xor(a, 1);
                a += __shfl_xor(a, 2);
                a += __shfl_xor(a, 4);
                a += __shfl_xor(a, 8);
                if (part == 0) sxb_nxt[row] = a;
            }

            // (4) PV epilogue: gate + out write
            #pragma unroll
            for (int nt = 0; nt < 4; ++nt) {
                const int d = nbase + nt * 16 + lane15;
                #pragma unroll
                for (int r = 0; r < 4; ++r) {
                    const int wtok = m0 + quad * 4 + r;
                    float g = xblk[wtok * CD + d];
                    oblk[wtok * CD + d] = acc[nt][r] * g;
                }
            }
        }
        __syncthreads();
    }
}

extern "C" void kernel_launch(void* const* d_in, const int* in_sizes, int n_in,
                              void* d_out, int out_size, void* d_ws, size_t ws_size,
                              hipStream_t stream) {
    const float* x  = (const float*)d_in[0];
    const float* wq = (const float*)d_in[1];
    // d_in[2] = bq: row-constant in softmax -> provably unused
    const float* wk = (const float*)d_in[3];
    const float* bk = (const float*)d_in[4];
    const float* wv = (const float*)d_in[5];
    const float* bv = (const float*)d_in[6];
    float* out = (float*)d_out;

    char* ws = (char*)d_ws;
    u16* Mthi   = (u16*)ws;                         // 128 KB
    u16* Mtlo   = (u16*)(ws + (128 << 10));         // 128 KB
    u16* Wvthi  = (u16*)(ws + (256 << 10));         // 128 KB
    float* wqbk = (float*)(ws + (384 << 10));       // 1 KB

    prep_m<<<128, 256, 0, stream>>>(wq, wk, Mthi, Mtlo);
    prep_v<<<16, 256, 0, stream>>>(wv, Wvthi);
    prep_b<<<16, 256, 0, stream>>>(wq, bk, wqbk);

    const size_t lds = (size_t)(4 * WD * XST * sizeof(u16)) +
                       (WD * SST + 2 * WD + CD) * sizeof(float);
    hipFuncSetAttribute((const void*)attn_kernel,
                        hipFuncAttributeMaxDynamicSharedMemorySize, (int)lds);
    attn_kernel<<<GRID, 1024, lds, stream>>>(x, Mthi, Mtlo, Wvthi, wqbk, bv, out);
}

// Round 5
// 374.335 us; speedup vs baseline: 1.2977x; 1.2977x over previous
//
#include <hip/hip_runtime.h>

#define CD   256
#define WD   64
#define NBH  2048
#define XST  264   // bf16 row stride for X/T tiles (256+8, keeps rows 16B-aligned)
#define VST  72    // bf16 row stride for Vt (64+8)
#define SST  68    // fp32 row stride for S (64+4)

typedef unsigned short u16;
typedef __attribute__((ext_vector_type(8))) short bfrag_t;  // 8 bf16 = 4 VGPR
typedef __attribute__((ext_vector_type(4))) float f4_t;

#define MFMA(a, b, c) __builtin_amdgcn_mfma_f32_16x16x32_bf16(a, b, c, 0, 0, 0)

__device__ __forceinline__ u16 f2bf(float f) {
    unsigned u = __float_as_uint(f);
    u += 0x7fffu + ((u >> 16) & 1u);          // round-to-nearest-even
    return (u16)(u >> 16);
}
__device__ __forceinline__ float bf2f(u16 h) {
    return __uint_as_float(((unsigned)h) << 16);
}

// ---------------------------------------------------------------------------
// prep_all: fused prep (one launch instead of three).
//   blocks 0..127   : Mt[d][c] = sum_f wk[c][f]*wq[d][f], split hi/lo bf16
//   blocks 128..143 : Wvt[d][c] = bf16(wv[c][d]) via LDS transpose
//   blocks 144..159 : wqbk[c] = sum_f wq[c][f]*bk[f]
// ---------------------------------------------------------------------------
__global__ __launch_bounds__(256) void prep_all(
    const float* __restrict__ wq, const float* __restrict__ wk,
    const float* __restrict__ wv, const float* __restrict__ bk,
    u16* __restrict__ Mthi, u16* __restrict__ Mtlo,
    u16* __restrict__ Wvthi, float* __restrict__ wqbk)
{
    __shared__ float smem[12336];     // 49344 B, unioned across branches
    const int t = threadIdx.x;
    const int b = blockIdx.x;

    if (b < 128) {
        // ---- prep_m ----
        float* swq = smem;            // [16][257]
        float* swk = smem + 16 * 257; // [32][257]
        const int dt = b >> 3;        // 16 d-tiles
        const int ct = b & 7;         // 8 c-tiles (32 c each)
        #pragma unroll
        for (int n = 0; n < 16; ++n) {
            int idx = n * 256 + t;    // 4096
            int d = idx >> 8, f = idx & 255;
            swq[d * 257 + f] = wq[(dt * 16 + d) * CD + f];
        }
        #pragma unroll
        for (int n = 0; n < 32; ++n) {
            int idx = n * 256 + t;    // 8192
            int c = idx >> 8, f = idx & 255;
            swk[c * 257 + f] = wk[(ct * 32 + c) * CD + f];
        }
        __syncthreads();
        const int d = t & 15, c0 = (t >> 4) * 2;
        #pragma unroll
        for (int cc = 0; cc < 2; ++cc) {
            const float* kr = &swk[(c0 + cc) * 257];
            const float* qr = &swq[d * 257];
            float acc = 0.f;
            #pragma unroll 8
            for (int f = 0; f < CD; ++f) acc = fmaf(kr[f], qr[f], acc);
            u16 h = f2bf(acc);
            int off = (dt * 16 + d) * CD + ct * 32 + c0 + cc;
            Mthi[off] = h;
            Mtlo[off] = f2bf(acc - bf2f(h));
        }
    } else if (b < 144) {
        // ---- prep_v ----
        float* tile = smem;           // [64][65]
        const int bb = b - 128;
        const int bc = bb >> 2, bd = bb & 3;
        #pragma unroll
        for (int n = 0; n < 16; ++n) {
            int idx = n * 256 + t;
            int c = idx >> 6, d = idx & 63;
            tile[c * 65 + d] = wv[(bc * 64 + c) * CD + bd * 64 + d];
        }
        __syncthreads();
        #pragma unroll
        for (int n = 0; n < 16; ++n) {
            int idx = n * 256 + t;
            int d = idx >> 6, c = idx & 63;
            Wvthi[(bd * 64 + d) * CD + bc * 64 + c] = f2bf(tile[c * 65 + d]);
        }
    } else {
        // ---- prep_b ----
        float* sbk = smem;            // [256]
        if (t < CD) sbk[t] = bk[t];
        __syncthreads();
        const int c = (b - 144) * 16 + (t >> 4), part = t & 15;
        const float* wr = wq + c * CD + part * 16;
        const float* br = sbk + part * 16;
        float a = 0.f;
        #pragma unroll
        for (int j = 0; j < 16; ++j) a = fmaf(wr[j], br[j], a);
        a += __shfl_xor(a, 1);
        a += __shfl_xor(a, 2);
        a += __shfl_xor(a, 4);
        a += __shfl_xor(a, 8);
        if (part == 0) wqbk[c] = a;
    }
}

// ---------------------------------------------------------------------------
// Main: one block per (b,h), 1024 threads = 16 waves (4 waves/SIMD,
// 1 block/CU). Round-0 phase structure (measured best, 209 us), plus:
//  - T/V phases: A-fragments (Mthi/Mtlo/Wvthi, L2-resident) batch-loaded
//    into registers before the kk loop (VGPR 44 showed the compiler was
//    serializing load->use per kk, exposing L2 latency 8x per phase).
//  - S phase: 3 independent MFMA chains (depth 8 instead of 24).
// ---------------------------------------------------------------------------
extern __shared__ char smem_raw[];

__global__ __launch_bounds__(1024, 4) void attn_kernel(
    const float* __restrict__ x,
    const u16* __restrict__ Mthi, const u16* __restrict__ Mtlo,
    const u16* __restrict__ Wvthi, const float* __restrict__ wqbk,
    const float* __restrict__ bv, float* __restrict__ out)
{
    u16* sXhi = (u16*)smem_raw;                 // [64][XST]
    u16* sXlo = sXhi + WD * XST;
    u16* sThi = sXlo + WD * XST;                // [64][XST] token-major T
    u16* sTlo = sThi + WD * XST;
    u16* sVt  = sThi;                           // alias: [256][VST] after S
    float* sS  = (float*)(sTlo + WD * XST);     // [64][SST]
    float* sxb = sS + WD * SST;                 // [64]
    float* sbv = sxb + WD;                      // [256]

    const int t = threadIdx.x;
    const int wave = t >> 6, lane = t & 63;
    const int lane15 = lane & 15, quad = lane >> 4;
    const int bh = blockIdx.x;
    const float* __restrict__ xblk = x + (size_t)bh * (WD * CD);
    float* __restrict__ oblk = out + (size_t)bh * (WD * CD);

    if (t < CD) sbv[t] = bv[t];
    // ---- stage X -> bf16 hi/lo --------------------------------------------
    {
        const float4* xv4 = (const float4*)xblk;
        #pragma unroll
        for (int n = 0; n < 4; ++n) {
            int idx = n * 1024 + t;             // 0..4095
            float4 v = xv4[idx];
            int i = idx >> 6;
            int c = (idx & 63) << 2;
            ushort4 h4, l4;
            h4.x = f2bf(v.x); l4.x = f2bf(v.x - bf2f(h4.x));
            h4.y = f2bf(v.y); l4.y = f2bf(v.y - bf2f(h4.y));
            h4.z = f2bf(v.z); l4.z = f2bf(v.z - bf2f(h4.z));
            h4.w = f2bf(v.w); l4.w = f2bf(v.w - bf2f(h4.w));
            *(ushort4*)&sXhi[i * XST + c] = h4;
            *(ushort4*)&sXlo[i * XST + c] = l4;
        }
    }
    // ---- xb[v] = x_v . (Wq bk)  (fp32, 16 lanes per row) ------------------
    {
        const int row = t >> 4, part = t & 15;
        const float* xr = xblk + row * CD + part * 16;
        const float* br = wqbk + part * 16;
        float a = 0.f;
        #pragma unroll
        for (int i = 0; i < 4; ++i) {
            float4 xv = *(const float4*)&xr[i * 4];
            float4 bvv = *(const float4*)&br[i * 4];
            a = fmaf(xv.x, bvv.x, a); a = fmaf(xv.y, bvv.y, a);
            a = fmaf(xv.z, bvv.z, a); a = fmaf(xv.w, bvv.w, a);
        }
        a += __shfl_xor(a, 1);
        a += __shfl_xor(a, 2);
        a += __shfl_xor(a, 4);
        a += __shfl_xor(a, 8);
        if (part == 0) sxb[row] = a;
    }
    __syncthreads();

    // ---- Phase T: Tt[d][i] = sum_c Mt[d][c]*X[i][c]  (split, 3 terms) -----
    // Wave w: d-tile w, all 4 token tiles. 96 MFMAs/wave.
    // A-frags batch-loaded first (16 outstanding L2 loads, one wait).
    {
        f4_t acc[4];
        const f4_t z = {0.f, 0.f, 0.f, 0.f};
        #pragma unroll
        for (int a = 0; a < 4; ++a) acc[a] = z;

        const int drow = wave * 16 + lane15;
        const u16* mh = Mthi + drow * CD + quad * 8;
        const u16* ml = Mtlo + drow * CD + quad * 8;
        bfrag_t Ah[8], Al[8];
        #pragma unroll
        for (int kk = 0; kk < 8; ++kk) {
            Ah[kk] = *(const bfrag_t*)(mh + kk * 32);
            Al[kk] = *(const bfrag_t*)(ml + kk * 32);
        }
        #pragma unroll
        for (int kk = 0; kk < 8; ++kk) {
            const int k0 = kk * 32 + quad * 8;
            bfrag_t Bh[4], Bl[4];
            #pragma unroll
            for (int nt = 0; nt < 4; ++nt) {
                const int xo = (nt * 16 + lane15) * XST + k0;
                Bh[nt] = *(const bfrag_t*)(sXhi + xo);
                Bl[nt] = *(const bfrag_t*)(sXlo + xo);
            }
            #pragma unroll
            for (int nt = 0; nt < 4; ++nt) {
                acc[nt] = MFMA(Ah[kk], Bh[nt], acc[nt]);
                acc[nt] = MFMA(Ah[kk], Bl[nt], acc[nt]);
                acc[nt] = MFMA(Al[kk], Bh[nt], acc[nt]);
            }
        }
        #pragma unroll
        for (int nt = 0; nt < 4; ++nt) {
            const int i  = nt * 16 + lane15;
            const int d0 = wave * 16 + quad * 4;
            ushort4 h4, l4;
            float f;
            f = acc[nt][0]; h4.x = f2bf(f); l4.x = f2bf(f - bf2f(h4.x));
            f = acc[nt][1]; h4.y = f2bf(f); l4.y = f2bf(f - bf2f(h4.y));
            f = acc[nt][2]; h4.z = f2bf(f); l4.z = f2bf(f - bf2f(h4.z));
            f = acc[nt][3]; h4.w = f2bf(f); l4.w = f2bf(f - bf2f(h4.w));
            *(ushort4*)&sThi[i * XST + d0] = h4;
            *(ushort4*)&sTlo[i * XST + d0] = l4;
        }
    }
    __syncthreads();

    // ---- Phase S: S[w][v] = sum_c T[w][c]*X[v][c] + xb[v]  (3 chains) -----
    {
        const f4_t z = {0.f, 0.f, 0.f, 0.f};
        f4_t a0 = z, a1 = z, a2 = z;
        const int m0 = (wave >> 2) * 16;
        const int n0 = (wave & 3) * 16;
        #pragma unroll
        for (int kk = 0; kk < 8; ++kk) {
            const int k0 = kk * 32 + quad * 8;
            const int to = (m0 + lane15) * XST + k0;
            const int xo = (n0 + lane15) * XST + k0;
            bfrag_t Th = *(const bfrag_t*)(sThi + to);
            bfrag_t Tl = *(const bfrag_t*)(sTlo + to);
            bfrag_t Xh = *(const bfrag_t*)(sXhi + xo);
            bfrag_t Xl = *(const bfrag_t*)(sXlo + xo);
            a0 = MFMA(Th, Xh, a0);
            a1 = MFMA(Th, Xl, a1);
            a2 = MFMA(Tl, Xh, a2);
        }
        const int v = n0 + lane15;
        const float xbv = sxb[v];
        #pragma unroll
        for (int r = 0; r < 4; ++r) {
            const int wtok = m0 + quad * 4 + r;
            sS[wtok * SST + v] = a0[r] + a1[r] + a2[r] + xbv;
        }
    }
    __syncthreads();

    // ---- Phase V: Vt[d][j] = sum_c Wvt[d][c]*Xhi[j][c] + bv[d] ------------
    // A-frags batch-loaded. Writes sVt (alias of sThi, safe: S done).
    {
        f4_t acc[4];
        const f4_t z = {0.f, 0.f, 0.f, 0.f};
        #pragma unroll
        for (int a = 0; a < 4; ++a) acc[a] = z;

        const int drow = wave * 16 + lane15;
        const u16* wvp = Wvthi + drow * CD + quad * 8;
        bfrag_t Av[8];
        #pragma unroll
        for (int kk = 0; kk < 8; ++kk)
            Av[kk] = *(const bfrag_t*)(wvp + kk * 32);
        #pragma unroll
        for (int kk = 0; kk < 8; ++kk) {
            const int k0 = kk * 32 + quad * 8;
            #pragma unroll
            for (int nt = 0; nt < 4; ++nt) {
                bfrag_t Bf = *(const bfrag_t*)(sXhi + (nt * 16 + lane15) * XST + k0);
                acc[nt] = MFMA(Av[kk], Bf, acc[nt]);
            }
        }
        #pragma unroll
        for (int nt = 0; nt < 4; ++nt) {
            const int j = nt * 16 + lane15;
            #pragma unroll
            for (int r = 0; r < 4; ++r) {
                const int d = wave * 16 + quad * 4 + r;
                sVt[d * VST + j] = f2bf(acc[nt][r] + sbv[d]);
            }
        }
    }
    // ---- softmax over v: 16 lanes per row, 4 elements each ----------------
    {
        const int row = t >> 4, part = t & 15;
        float* srow = &sS[row * SST + part * 4];
        float e[4];
        float mx = fmaxf(fmaxf(srow[0], srow[1]), fmaxf(srow[2], srow[3]));
        mx = fmaxf(mx, __shfl_xor(mx, 1));
        mx = fmaxf(mx, __shfl_xor(mx, 2));
        mx = fmaxf(mx, __shfl_xor(mx, 4));
        mx = fmaxf(mx, __shfl_xor(mx, 8));
        float sum = 0.f;
        #pragma unroll
        for (int u = 0; u < 4; ++u) { e[u] = __expf(srow[u] - mx); sum += e[u]; }
        sum += __shfl_xor(sum, 1);
        sum += __shfl_xor(sum, 2);
        sum += __shfl_xor(sum, 4);
        sum += __shfl_xor(sum, 8);
        float inv = 1.0f / sum;
        #pragma unroll
        for (int u = 0; u < 4; ++u) srow[u] = e[u] * inv;
    }
    __syncthreads();

    // ---- Phase PV: out[w][d] = (sum_j P[w][j]*Vt[d][j]) * x[w][d] ---------
    // Wave w: m-tile w&3, d-tiles (w>>2)*4 .. +3. 8 MFMAs/wave.
    {
        f4_t acc[4];
        const f4_t z = {0.f, 0.f, 0.f, 0.f};
        #pragma unroll
        for (int a = 0; a < 4; ++a) acc[a] = z;

        const int m0 = (wave & 3) * 16;
        const int nbase = (wave >> 2) * 64;
        #pragma unroll
        for (int kk = 0; kk < 2; ++kk) {
            const int k0 = kk * 32 + quad * 8;
            const float* p = &sS[(m0 + lane15) * SST + k0];
            f4_t p0 = *(const f4_t*)p;
            f4_t p1 = *(const f4_t*)(p + 4);
            bfrag_t Af;
            Af[0] = (short)f2bf(p0[0]); Af[1] = (short)f2bf(p0[1]);
            Af[2] = (short)f2bf(p0[2]); Af[3] = (short)f2bf(p0[3]);
            Af[4] = (short)f2bf(p1[0]); Af[5] = (short)f2bf(p1[1]);
            Af[6] = (short)f2bf(p1[2]); Af[7] = (short)f2bf(p1[3]);
            #pragma unroll
            for (int nt = 0; nt < 4; ++nt) {
                bfrag_t Bf = *(const bfrag_t*)(sVt + (nbase + nt * 16 + lane15) * VST + k0);
                acc[nt] = MFMA(Af, Bf, acc[nt]);
            }
        }
        #pragma unroll
        for (int nt = 0; nt < 4; ++nt) {
            const int d = nbase + nt * 16 + lane15;
            #pragma unroll
            for (int r = 0; r < 4; ++r) {
                const int wtok = m0 + quad * 4 + r;
                float g = xblk[wtok * CD + d];
                oblk[wtok * CD + d] = acc[nt][r] * g;
            }
        }
    }
}

extern "C" void kernel_launch(void* const* d_in, const int* in_sizes, int n_in,
                              void* d_out, int out_size, void* d_ws, size_t ws_size,
                              hipStream_t stream) {
    const float* x  = (const float*)d_in[0];
    const float* wq = (const float*)d_in[1];
    // d_in[2] = bq: row-constant in softmax -> provably unused
    const float* wk = (const float*)d_in[3];
    const float* bk = (const float*)d_in[4];
    const float* wv = (const float*)d_in[5];
    const float* bv = (const float*)d_in[6];
    float* out = (float*)d_out;

    char* ws = (char*)d_ws;
    u16* Mthi   = (u16*)ws;                         // 128 KB
    u16* Mtlo   = (u16*)(ws + (128 << 10));         // 128 KB
    u16* Wvthi  = (u16*)(ws + (256 << 10));         // 128 KB
    float* wqbk = (float*)(ws + (384 << 10));       // 1 KB

    prep_all<<<160, 256, 0, stream>>>(wq, wk, wv, bk, Mthi, Mtlo, Wvthi, wqbk);

    const size_t lds = (size_t)(4 * WD * XST * sizeof(u16)) +
                       (WD * SST + WD + CD) * sizeof(float);
    hipFuncSetAttribute((const void*)attn_kernel,
                        hipFuncAttributeMaxDynamicSharedMemorySize, (int)lds);
    attn_kernel<<<NBH, 1024, lds, stream>>>(x, Mthi, Mtlo, Wvthi, wqbk, bv, out);
}